// Round 2
// baseline (111.347 us; speedup 1.0000x reference)
//
#include <hip/hip_runtime.h>
#include <math.h>

// Correctly-rounded double constants: Cj = cos(j*pi/16), N0 = sqrt(1/8).
#define C1 0.9807852804032304
#define C2 0.9238795325112867
#define C3 0.8314696123025452
#define C4 0.7071067811865476
#define C5 0.5555702330196022
#define C6 0.3826834323650898
#define C7 0.19509032201612825
#define N0 0.35355339059327373

// DCT-II matrix M[k][n] = norm_k * cos(pi/8*(n+0.5)*k), fully compile-time.
static constexpr double Mc[8][8] = {
 {  N0,      N0,      N0,      N0,      N0,      N0,      N0,      N0    },
 {  .5*C1,   .5*C3,   .5*C5,   .5*C7,  -.5*C7,  -.5*C5,  -.5*C3,  -.5*C1 },
 {  .5*C2,   .5*C6,  -.5*C6,  -.5*C2,  -.5*C2,  -.5*C6,   .5*C6,   .5*C2 },
 {  .5*C3,  -.5*C7,  -.5*C1,  -.5*C5,   .5*C5,   .5*C1,   .5*C7,  -.5*C3 },
 {  .5*C4,  -.5*C4,  -.5*C4,   .5*C4,   .5*C4,  -.5*C4,  -.5*C4,   .5*C4 },
 {  .5*C5,  -.5*C1,   .5*C7,   .5*C3,  -.5*C3,  -.5*C7,   .5*C1,  -.5*C5 },
 {  .5*C6,  -.5*C2,   .5*C2,  -.5*C6,  -.5*C6,   .5*C2,  -.5*C2,   .5*C6 },
 {  .5*C7,  -.5*C5,   .5*C3,  -.5*C1,   .5*C1,  -.5*C3,   .5*C5,  -.5*C7 },
};
// f32 copy for the post-quantization (smooth) path.
#define ROWF(r) {(float)Mc[r][0],(float)Mc[r][1],(float)Mc[r][2],(float)Mc[r][3],\
                 (float)Mc[r][4],(float)Mc[r][5],(float)Mc[r][6],(float)Mc[r][7]}
static constexpr float Mcf[8][8] = {ROWF(0),ROWF(1),ROWF(2),ROWF(3),ROWF(4),ROWF(5),ROWF(6),ROWF(7)};

// JPEG base quantization tables (exact integers)
static __device__ const double LUM_BASE[64] = {
 16,11,10,16,24,40,51,61,
 12,12,14,19,26,58,60,55,
 14,13,16,24,40,57,69,56,
 14,17,22,29,51,87,80,62,
 18,22,37,56,68,109,103,77,
 24,35,55,64,81,104,113,92,
 49,64,78,87,103,121,120,101,
 72,92,95,98,112,100,103,99};
static __device__ const double CHROM_BASE[64] = {
 17,18,24,47,99,99,99,99,
 18,21,26,66,99,99,99,99,
 24,26,56,99,99,99,99,99,
 47,66,99,99,99,99,99,99,
 99,99,99,99,99,99,99,99,
 99,99,99,99,99,99,99,99,
 99,99,99,99,99,99,99,99,
 99,99,99,99,99,99,99,99};

// One thread = one ROW of one 8x8 block of one channel.
// Workgroup = 192 threads = 3 waves; wave w = channel w of an 8x64 strip.
// Pre-cliff (DCT+quant) f64; post-cliff f32.
// Round 9: (1) f64 div -> reciprocal + fma refinement (bit-identical),
// (2) even-odd symmetry decomposition of all 8-point transforms (64->40 ops),
// (3) x255 folded into YCbCr weights at compile time.
// Round 10: quant-table build done by wave 0 ONLY, published via barrier #1.
// Round 11: P4 (final IDCT) computed ONCE per channel (own wave only, 40 ops
// instead of 120) — IDCT pixel rows exchanged through LDS (upper half of each
// wave's U chunk, dead after transpose-1) + barrier #3. Color-back expression
// trees unchanged -> bit-identical output.
__global__ __launch_bounds__(192, 4) void jpeg_fwd(const float* __restrict__ img,
                                                   const int* __restrict__ quality,
                                                   float* __restrict__ out)
{
    __shared__ double QT[128];     // [2][8][8] scaled quant tables, f64
    __shared__ double RQ[128];     // reciprocals 1/QT (correctly rounded)
    __shared__ double U[1728];     // 13824 B; per-wave chunk = U + w*576 (4608 B)

    const int t   = threadIdx.x;
    const int w   = t >> 6;      // channel = wave id (wave-uniform)
    const int l   = t & 63;
    const int blk = l >> 3;      // block within strip (0..7)
    const int rr  = l & 7;       // row within block

    const int b    = blockIdx.x >> 9;   // image index
    const int rem  = blockIdx.x & 511;
    const int row0 = (rem >> 3) << 3;   // strip row * 8
    const int col0 = (rem & 7) << 6;    // strip col * 64

    const size_t plane = 512 * 512;

    // ---- Issue global loads early (my row's 8 px, all 3 planes, float4)
    const float* p = img + (size_t)(b * 3) * plane + (size_t)(row0 + rr) * 512 + col0 + blk * 8;
    float4 R0 = *(const float4*)(p);
    float4 R1 = *(const float4*)(p + 4);
    float4 G0 = *(const float4*)(p + plane);
    float4 G1 = *(const float4*)(p + plane + 4);
    float4 B0 = *(const float4*)(p + 2 * plane);
    float4 B1 = *(const float4*)(p + 2 * plane + 4);

    // ---- Build quant tables + reciprocals in LDS — WAVE 0 ONLY (uniform
    // branch, s_cbranch). Identical arithmetic to the all-waves version ->
    // bit-identical table. Published to waves 1-2 by barrier #1 below.
    if (w == 0) {
        int q = quality[0];
        q = q < 1 ? 1 : (q > 100 ? 100 : q);
        double scale = (q < 50) ? (5000.0 / (double)q) : (200.0 - 2.0 * (double)q);
        #pragma unroll
        for (int h = 0; h < 2; ++h) {
            int e = l + (h << 6);           // entries l and l+64 -> covers 0..127
            int tbl = e >> 6, idx = e & 63;
            double base = tbl ? CHROM_BASE[idx] : LUM_BASE[idx];
            double v = (base * scale + 50.0) / 100.0;
            v = fmin(fmax(v, 1.0), 255.0);
            QT[e] = v;
            RQ[e] = 1.0 / v;
        }
    }

    // YCbCr weights with x255 folded in at compile time (f64 products).
    const double F00 =  0.299 * 255.0,  F01 =  0.587 * 255.0,  F02 =  0.114 * 255.0;
    const double F10 = -0.1687 * 255.0, F11 = -0.3313 * 255.0, F12 =  0.5 * 255.0;
    const double F20 =  0.5 * 255.0,    F21 = -0.4187 * 255.0, F22 = -0.0813 * 255.0;

    float rf[8] = {R0.x, R0.y, R0.z, R0.w, R1.x, R1.y, R1.z, R1.w};
    float gf[8] = {G0.x, G0.y, G0.z, G0.w, G1.x, G1.y, G1.z, G1.w};
    float bf[8] = {B0.x, B0.y, B0.z, B0.w, B1.x, B1.y, B1.z, B1.w};

    // ---- Color convert (my channel only); keep +128 then -128 (both
    // roundings, matching np) — they do NOT cancel exactly in f64.
    double row[8];
    #pragma unroll
    for (int k = 0; k < 8; ++k) {
        double rv = (double)rf[k];
        double gv = (double)gf[k];
        double bv = (double)bf[k];
        double v;
        if (w == 0)      v = F00 * rv + F01 * gv + F02 * bv;
        else if (w == 1) v = F10 * rv + F11 * gv + F12 * bv + 128.0;
        else             v = F20 * rv + F21 * gv + F22 * bv + 128.0;
        row[k] = v - 128.0;
    }

    // ---- P1: row @ M^T via even-odd symmetry (f64, 8 add + 32 FMA)
    // y[c] = sum_{k=0..3} (row[k] + (-1)^c row[7-k]) * Mc[c][k]
    double y[8];
    {
        double u0[4], v0[4];
        #pragma unroll
        for (int k = 0; k < 4; ++k) {
            u0[k] = row[k] + row[7 - k];
            v0[k] = row[k] - row[7 - k];
        }
        #pragma unroll
        for (int c = 0; c < 8; c += 2) {
            double se = 0.0, so = 0.0;
            #pragma unroll
            for (int k = 0; k < 4; ++k) {
                se += u0[k] * Mc[c][k];
                so += v0[k] * Mc[c + 1][k];
            }
            y[c] = se; y[c + 1] = so;
        }
    }

    // ---- Transpose 1 (f64, pad-9, own-wave chunk — IN-WAVE, no barrier)
    {
        double* tb = U + w * 576 + blk * 72 + rr * 9;
        #pragma unroll
        for (int k = 0; k < 8; ++k) tb[k] = y[k];
    }
    double t1[8], qv[8], rv8[8];
    {
        const double* tb = U + w * 576 + blk * 72 + rr;
        #pragma unroll
        for (int k = 0; k < 8; ++k) t1[k] = tb[k * 9];
    }

    __syncthreads();   // barrier #1: publish wave-0's QT/RQ to waves 1-2

    const int sel = ((b * 3 + w) < 16) ? 0 : 1;   // reference's flattened-index quirk
    #pragma unroll
    for (int j = 0; j < 8; ++j) {
        qv[j]  = QT[(sel << 6) + (j << 3) + rr];
        rv8[j] = RQ[(sel << 6) + (j << 3) + rr];
    }

    // ---- P2: column DCT (even-odd) + quantize tq = rint(s/q)*q.
    // Division via reciprocal + one fma refinement: correctly rounded,
    // bit-identical to hardware s/q (Markstein).
    double wq[8];
    {
        double tu[4], tv[4];
        #pragma unroll
        for (int k = 0; k < 4; ++k) {
            tu[k] = t1[k] + t1[7 - k];
            tv[k] = t1[k] - t1[7 - k];
        }
        #pragma unroll
        for (int j = 0; j < 8; j += 2) {
            double se = 0.0, so = 0.0;
            #pragma unroll
            for (int k = 0; k < 4; ++k) {
                se += tu[k] * Mc[j][k];
                so += tv[k] * Mc[j + 1][k];
            }
            // even j
            {
                double q = qv[j], r = rv8[j];
                double qh = se * r;
                double e  = fma(-q, qh, se);
                double qq = fma(e, r, qh);
                wq[j] = rint(qq) * q;
            }
            // odd j
            {
                double q = qv[j + 1], r = rv8[j + 1];
                double qh = so * r;
                double e  = fma(-q, qh, so);
                double qq = fma(e, r, qh);
                wq[j + 1] = rint(qq) * q;
            }
        }
    }

    // ======== post-cliff: f32 from here on ========
    float wqf[8];
    #pragma unroll
    for (int k = 0; k < 8; ++k) wqf[k] = (float)wq[k];

    // ---- P3: (tq^T row) @ M (f32, even-odd over output index j)
    // a3[j] = pe+po, a3[7-j] = pe-po;  pe from even k, po from odd k.
    float a3[8];
    #pragma unroll
    for (int j = 0; j < 4; ++j) {
        float pe = 0.0f, po = 0.0f;
        #pragma unroll
        for (int k = 0; k < 4; ++k) {
            pe += wqf[2 * k]     * Mcf[2 * k][j];
            po += wqf[2 * k + 1] * Mcf[2 * k + 1][j];
        }
        a3[j]     = pe + po;
        a3[7 - j] = pe - po;
    }

    float* fU = (float*)U;   // f32 view of U. Per-wave chunk = 1152 floats.
    // Chunk map (floats, per wave w, base w*1152):
    //   [0   .. 576)  : A3 transpose buffer (pad-9), live T2 -> A3-read
    //   [576 .. 1088) : IDCT pixel rows [blk][rr][8], live after barrier #3
    // (region [576..1088) overlays bytes 2304..4352 of the f64 T1 chunk,
    //  which is dead after the t1[] reads above)

    // ---- Transpose 2 write (f32, pad-9) into MY OWN wave's chunk
    {
        float* tb = fU + w * 1152 + blk * 72 + rr * 9;
        #pragma unroll
        for (int k = 0; k < 8; ++k) tb[k] = a3[k];
    }
    __syncthreads();   // barrier #2: A3 ready

    // ---- Read row rr of A3 for MY OWN channel only (stride-9 f32, 2-way = free)
    float tC[8];
    {
        const float* c = fU + w * 1152 + blk * 72 + rr;
        #pragma unroll
        for (int k = 0; k < 8; ++k) tC[k] = c[k * 9];
    }

    // ---- P4 (f32, even-odd): final IDCT row rr — OWN channel only (40 ops)
    float pr[8];
    #pragma unroll
    for (int j = 0; j < 4; ++j) {
        float e = 0.0f, o = 0.0f;
        #pragma unroll
        for (int k = 0; k < 4; ++k) {
            e += tC[2 * k]     * Mcf[2 * k][j];
            o += tC[2 * k + 1] * Mcf[2 * k + 1][j];
        }
        pr[j]     = e + o;
        pr[7 - j] = e - o;
    }

    // ---- Publish my channel's raw IDCT pixel row (contiguous float4 x2)
    {
        float* prw = fU + w * 1152 + 576 + blk * 64 + rr * 8;
        *(float4*)(prw)     = make_float4(pr[0], pr[1], pr[2], pr[3]);
        *(float4*)(prw + 4) = make_float4(pr[4], pr[5], pr[6], pr[7]);
    }
    __syncthreads();   // barrier #3: pixel rows of all 3 channels ready

    // ---- Color back (f32): fetch only the foreign channels this plane needs.
    // Expression trees identical to the fused version -> bit-identical output.
    const int pixoff = 576 + blk * 64 + rr * 8;
    float o[8];
    if (w == 0) {
        // R = (Y+128) + 1.402*Cr       (Y = own pr, Cr from wave 2)
        float4 cr0 = *(const float4*)(fU + 2 * 1152 + pixoff);
        float4 cr1 = *(const float4*)(fU + 2 * 1152 + pixoff + 4);
        float crv[8] = {cr0.x, cr0.y, cr0.z, cr0.w, cr1.x, cr1.y, cr1.z, cr1.w};
        #pragma unroll
        for (int k = 0; k < 8; ++k) {
            float yd = pr[k] + 128.0f;
            float v  = yd + 1.402f * crv[k];
            o[k] = fminf(fmaxf(v * (1.0f / 255.0f), 0.0f), 1.0f);
        }
    } else if (w == 1) {
        // G = (Y+128) - 0.34414*Cb - 0.71414*Cr   (Cb = own pr; Y, Cr from LDS)
        float4 y0  = *(const float4*)(fU + 0 * 1152 + pixoff);
        float4 y1  = *(const float4*)(fU + 0 * 1152 + pixoff + 4);
        float4 cr0 = *(const float4*)(fU + 2 * 1152 + pixoff);
        float4 cr1 = *(const float4*)(fU + 2 * 1152 + pixoff + 4);
        float yv [8] = {y0.x,  y0.y,  y0.z,  y0.w,  y1.x,  y1.y,  y1.z,  y1.w};
        float crv[8] = {cr0.x, cr0.y, cr0.z, cr0.w, cr1.x, cr1.y, cr1.z, cr1.w};
        #pragma unroll
        for (int k = 0; k < 8; ++k) {
            float yd = yv[k] + 128.0f;
            float v  = yd - 0.34414f * pr[k] - 0.71414f * crv[k];
            o[k] = fminf(fmaxf(v * (1.0f / 255.0f), 0.0f), 1.0f);
        }
    } else {
        // B = (Y+128) + 1.772*Cb       (Cr = own pr, unused; Y, Cb from LDS)
        float4 y0  = *(const float4*)(fU + 0 * 1152 + pixoff);
        float4 y1  = *(const float4*)(fU + 0 * 1152 + pixoff + 4);
        float4 cb0 = *(const float4*)(fU + 1 * 1152 + pixoff);
        float4 cb1 = *(const float4*)(fU + 1 * 1152 + pixoff + 4);
        float yv [8] = {y0.x,  y0.y,  y0.z,  y0.w,  y1.x,  y1.y,  y1.z,  y1.w};
        float cbv[8] = {cb0.x, cb0.y, cb0.z, cb0.w, cb1.x, cb1.y, cb1.z, cb1.w};
        #pragma unroll
        for (int k = 0; k < 8; ++k) {
            float yd = yv[k] + 128.0f;
            float v  = yd + 1.772f * cbv[k];
            o[k] = fminf(fmaxf(v * (1.0f / 255.0f), 0.0f), 1.0f);
        }
    }

    // ---- Store (my wave writes plane w), coalesced float4 x2
    float* q0 = out + (size_t)(b * 3 + w) * plane + (size_t)(row0 + rr) * 512 + col0 + blk * 8;
    *(float4*)(q0)     = make_float4(o[0], o[1], o[2], o[3]);
    *(float4*)(q0 + 4) = make_float4(o[4], o[5], o[6], o[7]);
}

extern "C" void kernel_launch(void* const* d_in, const int* in_sizes, int n_in,
                              void* d_out, int out_size, void* d_ws, size_t ws_size,
                              hipStream_t stream) {
    const float* img     = (const float*)d_in[0];
    const int*   quality = (const int*)d_in[1];
    float*       out     = (float*)d_out;
    // 16 images x 64 row-strips x 8 col-strips = 8192 workgroups x 192 threads
    jpeg_fwd<<<8192, 192, 0, stream>>>(img, quality, out);
}

// Round 4
// 106.220 us; speedup vs baseline: 1.0483x; 1.0483x over previous
//
#include <hip/hip_runtime.h>
#include <math.h>

// Correctly-rounded double constants: Cj = cos(j*pi/16), N0 = sqrt(1/8).
#define C1 0.9807852804032304
#define C2 0.9238795325112867
#define C3 0.8314696123025452
#define C4 0.7071067811865476
#define C5 0.5555702330196022
#define C6 0.3826834323650898
#define C7 0.19509032201612825
#define N0 0.35355339059327373

// DCT-II matrix M[k][n] = norm_k * cos(pi/8*(n+0.5)*k), fully compile-time.
static constexpr double Mc[8][8] = {
 {  N0,      N0,      N0,      N0,      N0,      N0,      N0,      N0    },
 {  .5*C1,   .5*C3,   .5*C5,   .5*C7,  -.5*C7,  -.5*C5,  -.5*C3,  -.5*C1 },
 {  .5*C2,   .5*C6,  -.5*C6,  -.5*C2,  -.5*C2,  -.5*C6,   .5*C6,   .5*C2 },
 {  .5*C3,  -.5*C7,  -.5*C1,  -.5*C5,   .5*C5,   .5*C1,   .5*C7,  -.5*C3 },
 {  .5*C4,  -.5*C4,  -.5*C4,   .5*C4,   .5*C4,  -.5*C4,  -.5*C4,   .5*C4 },
 {  .5*C5,  -.5*C1,   .5*C7,   .5*C3,  -.5*C3,  -.5*C7,   .5*C1,  -.5*C5 },
 {  .5*C6,  -.5*C2,   .5*C2,  -.5*C6,  -.5*C6,   .5*C2,  -.5*C2,   .5*C6 },
 {  .5*C7,  -.5*C5,   .5*C3,  -.5*C1,   .5*C1,  -.5*C3,   .5*C5,  -.5*C7 },
};
// f32 copy for the post-quantization (smooth) path.
#define ROWF(r) {(float)Mc[r][0],(float)Mc[r][1],(float)Mc[r][2],(float)Mc[r][3],\
                 (float)Mc[r][4],(float)Mc[r][5],(float)Mc[r][6],(float)Mc[r][7]}
static constexpr float Mcf[8][8] = {ROWF(0),ROWF(1),ROWF(2),ROWF(3),ROWF(4),ROWF(5),ROWF(6),ROWF(7)};

// JPEG base quantization tables (exact integers)
static __device__ const double LUM_BASE[64] = {
 16,11,10,16,24,40,51,61,
 12,12,14,19,26,58,60,55,
 14,13,16,24,40,57,69,56,
 14,17,22,29,51,87,80,62,
 18,22,37,56,68,109,103,77,
 24,35,55,64,81,104,113,92,
 49,64,78,87,103,121,120,101,
 72,92,95,98,112,100,103,99};
static __device__ const double CHROM_BASE[64] = {
 17,18,24,47,99,99,99,99,
 18,21,26,66,99,99,99,99,
 24,26,56,99,99,99,99,99,
 47,66,99,99,99,99,99,99,
 99,99,99,99,99,99,99,99,
 99,99,99,99,99,99,99,99,
 99,99,99,99,99,99,99,99,
 99,99,99,99,99,99,99,99};

// Wave-level LDS fence: pins compiler ordering (memory clobber) AND drains
// LDS writes (lgkmcnt). Replaces __syncthreads() for 1-wave blocks.
#define WAVE_FENCE() asm volatile("s_waitcnt lgkmcnt(0)" ::: "memory")

// Round 13: ONE WAVE PER STRIP, all 3 channels per thread, ZERO barriers.
// (Round 12 failed: with no __syncthreads(), TBAA let the compiler reorder
//  f32 LDS ops against f64 LDS ops aliasing the same buffer. Fix: separate
//  distinctly-typed buffers U64/U32 + explicit wave fences.)
// One thread = one ROW of one 8x8 block; channel loop inside the thread.
// - Both transposes are in-wave (lockstep wave64 + fence) -> no syncthreads.
// - QT/RQ build: all-lanes 2-entries-each (proven R0 pattern), in-wave RAW.
// - P4 computed once per channel; color-back entirely in registers.
// - Global input traffic 1x (was 3x: every wave loaded all 3 planes).
// All per-channel expression trees are textually identical to the last
// passing kernel -> bit-identical output.
__global__ __launch_bounds__(64, 3) void jpeg_fwd(const float* __restrict__ img,
                                                  const int* __restrict__ quality,
                                                  float* __restrict__ out)
{
    __shared__ double QT[128];     // [2][8][8] scaled quant tables, f64
    __shared__ double RQ[128];     // reciprocals 1/QT (correctly rounded)
    __shared__ double U64[576];    // f64 transpose-1 buffer (pad-9), 4608 B
    __shared__ float  U32[576];    // f32 transpose-2 buffer (pad-9), 2304 B

    const int l   = threadIdx.x;   // 0..63
    const int blk = l >> 3;        // block within strip (0..7)
    const int rr  = l & 7;         // row within block

    const int b    = blockIdx.x >> 9;   // image index
    const int rem  = blockIdx.x & 511;
    const int row0 = (rem >> 3) << 3;   // strip row * 8
    const int col0 = (rem & 7) << 6;    // strip col * 64

    const size_t plane = 512 * 512;

    // ---- Issue global loads early (my row's 8 px, all 3 planes, float4)
    const float* p = img + (size_t)(b * 3) * plane + (size_t)(row0 + rr) * 512 + col0 + blk * 8;
    float4 R0 = *(const float4*)(p);
    float4 R1 = *(const float4*)(p + 4);
    float4 G0 = *(const float4*)(p + plane);
    float4 G1 = *(const float4*)(p + plane + 4);
    float4 B0 = *(const float4*)(p + 2 * plane);
    float4 B1 = *(const float4*)(p + 2 * plane + 4);

    // ---- Build quant tables + reciprocals in LDS — all 64 lanes, 2 entries
    // each (R0 pattern). Cross-lane RAW protected by the wave fence below.
    {
        int q = quality[0];
        q = q < 1 ? 1 : (q > 100 ? 100 : q);
        double scale = (q < 50) ? (5000.0 / (double)q) : (200.0 - 2.0 * (double)q);
        #pragma unroll
        for (int h = 0; h < 2; ++h) {
            int e = l + (h << 6);           // entries l and l+64 -> covers 0..127
            int tbl = e >> 6, idx = e & 63;
            double base = tbl ? CHROM_BASE[idx] : LUM_BASE[idx];
            double v = (base * scale + 50.0) / 100.0;
            v = fmin(fmax(v, 1.0), 255.0);
            QT[e] = v;
            RQ[e] = 1.0 / v;
        }
    }
    WAVE_FENCE();   // QT/RQ visible to all lanes of this (only) wave

    // YCbCr weights with x255 folded in at compile time (f64 products).
    const double F00 =  0.299 * 255.0,  F01 =  0.587 * 255.0,  F02 =  0.114 * 255.0;
    const double F10 = -0.1687 * 255.0, F11 = -0.3313 * 255.0, F12 =  0.5 * 255.0;
    const double F20 =  0.5 * 255.0,    F21 = -0.4187 * 255.0, F22 = -0.0813 * 255.0;

    float rf[8] = {R0.x, R0.y, R0.z, R0.w, R1.x, R1.y, R1.z, R1.w};
    float gf[8] = {G0.x, G0.y, G0.z, G0.w, G1.x, G1.y, G1.z, G1.w};
    float bf[8] = {B0.x, B0.y, B0.z, B0.w, B1.x, B1.y, B1.z, B1.w};

    // Quant-table column loads (qv/rv for column rr of table sel).
    double qv[8], rv8[8];
    int sel_cur = ((b * 3 + 0) < 16) ? 0 : 1;   // reference's flattened-index quirk
    #pragma unroll
    for (int j = 0; j < 8; ++j) {
        qv[j]  = QT[(sel_cur << 6) + (j << 3) + rr];
        rv8[j] = RQ[(sel_cur << 6) + (j << 3) + rr];
    }

    float pix0[8], pix1[8], pix2[8];   // final IDCT pixel rows Y, Cb, Cr

    // ================= per-channel pipeline (macro: CIDX is a literal) =====
#define CHANNEL_BODY(CIDX, PIXARR, COLOR_EXPR)                                  \
    {                                                                           \
        /* sel for this channel; reload qv/rv only when it changes (b=5) */     \
        int sel_c = ((b * 3 + CIDX) < 16) ? 0 : 1;                              \
        if (sel_c != sel_cur) {                                                 \
            sel_cur = sel_c;                                                    \
            _Pragma("unroll")                                                   \
            for (int j = 0; j < 8; ++j) {                                       \
                qv[j]  = QT[(sel_cur << 6) + (j << 3) + rr];                    \
                rv8[j] = RQ[(sel_cur << 6) + (j << 3) + rr];                    \
            }                                                                   \
        }                                                                       \
        /* ---- Color convert (f64), keep +128 then -128 (both roundings) */   \
        double row[8];                                                          \
        _Pragma("unroll")                                                       \
        for (int k = 0; k < 8; ++k) {                                           \
            double rv = (double)rf[k];                                          \
            double gv = (double)gf[k];                                          \
            double bv = (double)bf[k];                                          \
            double v  = (COLOR_EXPR);                                           \
            row[k] = v - 128.0;                                                 \
        }                                                                       \
        /* ---- P1: row @ M^T via even-odd symmetry (f64) */                    \
        double y[8];                                                            \
        {                                                                       \
            double u0[4], v0[4];                                                \
            _Pragma("unroll")                                                   \
            for (int k = 0; k < 4; ++k) {                                       \
                u0[k] = row[k] + row[7 - k];                                    \
                v0[k] = row[k] - row[7 - k];                                    \
            }                                                                   \
            _Pragma("unroll")                                                   \
            for (int c = 0; c < 8; c += 2) {                                    \
                double se = 0.0, so = 0.0;                                      \
                _Pragma("unroll")                                               \
                for (int k = 0; k < 4; ++k) {                                   \
                    se += u0[k] * Mc[c][k];                                     \
                    so += v0[k] * Mc[c + 1][k];                                 \
                }                                                               \
                y[c] = se; y[c + 1] = so;                                       \
            }                                                                   \
        }                                                                       \
        /* ---- Transpose 1 (f64, pad-9, in-wave, fenced) */                    \
        {                                                                       \
            double* tb = U64 + blk * 72 + rr * 9;                               \
            _Pragma("unroll")                                                   \
            for (int k = 0; k < 8; ++k) tb[k] = y[k];                           \
        }                                                                       \
        WAVE_FENCE();                                                           \
        double t1[8];                                                           \
        {                                                                       \
            const double* tb = U64 + blk * 72 + rr;                             \
            _Pragma("unroll")                                                   \
            for (int k = 0; k < 8; ++k) t1[k] = tb[k * 9];                      \
        }                                                                       \
        /* ---- P2: column DCT (even-odd) + quantize tq = rint(s/q)*q */        \
        double wq[8];                                                           \
        {                                                                       \
            double tu[4], tv[4];                                                \
            _Pragma("unroll")                                                   \
            for (int k = 0; k < 4; ++k) {                                       \
                tu[k] = t1[k] + t1[7 - k];                                      \
                tv[k] = t1[k] - t1[7 - k];                                      \
            }                                                                   \
            _Pragma("unroll")                                                   \
            for (int j = 0; j < 8; j += 2) {                                    \
                double se = 0.0, so = 0.0;                                      \
                _Pragma("unroll")                                               \
                for (int k = 0; k < 4; ++k) {                                   \
                    se += tu[k] * Mc[j][k];                                     \
                    so += tv[k] * Mc[j + 1][k];                                 \
                }                                                               \
                { /* even j: Markstein reciprocal division, bit-identical */    \
                    double q = qv[j], r = rv8[j];                               \
                    double qh = se * r;                                         \
                    double e  = fma(-q, qh, se);                                \
                    double qq = fma(e, r, qh);                                  \
                    wq[j] = rint(qq) * q;                                       \
                }                                                               \
                { /* odd j */                                                   \
                    double q = qv[j + 1], r = rv8[j + 1];                       \
                    double qh = so * r;                                         \
                    double e  = fma(-q, qh, so);                                \
                    double qq = fma(e, r, qh);                                  \
                    wq[j + 1] = rint(qq) * q;                                   \
                }                                                               \
            }                                                                   \
        }                                                                       \
        /* ======== post-cliff: f32 ======== */                                 \
        float wqf[8];                                                           \
        _Pragma("unroll")                                                       \
        for (int k = 0; k < 8; ++k) wqf[k] = (float)wq[k];                      \
        /* ---- P3: (tq^T row) @ M (f32, even-odd over output index j) */       \
        float a3[8];                                                            \
        _Pragma("unroll")                                                       \
        for (int j = 0; j < 4; ++j) {                                           \
            float pe = 0.0f, po = 0.0f;                                         \
            _Pragma("unroll")                                                   \
            for (int k = 0; k < 4; ++k) {                                       \
                pe += wqf[2 * k]     * Mcf[2 * k][j];                           \
                po += wqf[2 * k + 1] * Mcf[2 * k + 1][j];                       \
            }                                                                   \
            a3[j]     = pe + po;                                                \
            a3[7 - j] = pe - po;                                                \
        }                                                                       \
        /* ---- Transpose 2 (f32, pad-9, in-wave, fenced; own buffer) */        \
        {                                                                       \
            float* tb = U32 + blk * 72 + rr * 9;                                \
            _Pragma("unroll")                                                   \
            for (int k = 0; k < 8; ++k) tb[k] = a3[k];                          \
        }                                                                       \
        WAVE_FENCE();                                                           \
        float tC[8];                                                            \
        {                                                                       \
            const float* c2 = U32 + blk * 72 + rr;                              \
            _Pragma("unroll")                                                   \
            for (int k = 0; k < 8; ++k) tC[k] = c2[k * 9];                      \
        }                                                                       \
        /* ---- P4 (f32, even-odd): final IDCT row rr for this channel */       \
        _Pragma("unroll")                                                       \
        for (int j = 0; j < 4; ++j) {                                           \
            float e = 0.0f, o = 0.0f;                                           \
            _Pragma("unroll")                                                   \
            for (int k = 0; k < 4; ++k) {                                       \
                e += tC[2 * k]     * Mcf[2 * k][j];                             \
                o += tC[2 * k + 1] * Mcf[2 * k + 1][j];                         \
            }                                                                   \
            PIXARR[j]     = e + o;                                              \
            PIXARR[7 - j] = e - o;                                              \
        }                                                                       \
        WAVE_FENCE(); /* WAR: next channel's LDS writes must stay behind */     \
    }

    CHANNEL_BODY(0, pix0, F00 * rv + F01 * gv + F02 * bv)
    CHANNEL_BODY(1, pix1, F10 * rv + F11 * gv + F12 * bv + 128.0)
    CHANNEL_BODY(2, pix2, F20 * rv + F21 * gv + F22 * bv + 128.0)
#undef CHANNEL_BODY

    // ---- Color back (f32), all in registers; exact same expression trees.
    float oR[8], oG[8], oB[8];
    #pragma unroll
    for (int k = 0; k < 8; ++k) {
        float yd = pix0[k] + 128.0f;
        float vR = yd + 1.402f * pix2[k];
        float vG = yd - 0.34414f * pix1[k] - 0.71414f * pix2[k];
        float vB = yd + 1.772f * pix1[k];
        oR[k] = fminf(fmaxf(vR * (1.0f / 255.0f), 0.0f), 1.0f);
        oG[k] = fminf(fmaxf(vG * (1.0f / 255.0f), 0.0f), 1.0f);
        oB[k] = fminf(fmaxf(vB * (1.0f / 255.0f), 0.0f), 1.0f);
    }

    // ---- Stores: 3 planes x 2 float4, coalesced per instruction
    const size_t rowoff = (size_t)(row0 + rr) * 512 + col0 + blk * 8;
    float* qR = out + (size_t)(b * 3 + 0) * plane + rowoff;
    float* qG = out + (size_t)(b * 3 + 1) * plane + rowoff;
    float* qB = out + (size_t)(b * 3 + 2) * plane + rowoff;
    *(float4*)(qR)     = make_float4(oR[0], oR[1], oR[2], oR[3]);
    *(float4*)(qR + 4) = make_float4(oR[4], oR[5], oR[6], oR[7]);
    *(float4*)(qG)     = make_float4(oG[0], oG[1], oG[2], oG[3]);
    *(float4*)(qG + 4) = make_float4(oG[4], oG[5], oG[6], oG[7]);
    *(float4*)(qB)     = make_float4(oB[0], oB[1], oB[2], oB[3]);
    *(float4*)(qB + 4) = make_float4(oB[4], oB[5], oB[6], oB[7]);
}

extern "C" void kernel_launch(void* const* d_in, const int* in_sizes, int n_in,
                              void* d_out, int out_size, void* d_ws, size_t ws_size,
                              hipStream_t stream) {
    const float* img     = (const float*)d_in[0];
    const int*   quality = (const int*)d_in[1];
    float*       out     = (float*)d_out;
    // 16 images x 64 row-strips x 8 col-strips = 8192 strips, 1 wave each
    jpeg_fwd<<<8192, 64, 0, stream>>>(img, quality, out);
}

// Round 5
// 105.080 us; speedup vs baseline: 1.0596x; 1.0109x over previous
//
#include <hip/hip_runtime.h>
#include <math.h>

// Correctly-rounded double constants: Cj = cos(j*pi/16), N0 = sqrt(1/8).
#define C1 0.9807852804032304
#define C2 0.9238795325112867
#define C3 0.8314696123025452
#define C4 0.7071067811865476
#define C5 0.5555702330196022
#define C6 0.3826834323650898
#define C7 0.19509032201612825
#define N0 0.35355339059327373

// DCT-II matrix M[k][n] = norm_k * cos(pi/8*(n+0.5)*k), fully compile-time.
static constexpr double Mc[8][8] = {
 {  N0,      N0,      N0,      N0,      N0,      N0,      N0,      N0    },
 {  .5*C1,   .5*C3,   .5*C5,   .5*C7,  -.5*C7,  -.5*C5,  -.5*C3,  -.5*C1 },
 {  .5*C2,   .5*C6,  -.5*C6,  -.5*C2,  -.5*C2,  -.5*C6,   .5*C6,   .5*C2 },
 {  .5*C3,  -.5*C7,  -.5*C1,  -.5*C5,   .5*C5,   .5*C1,   .5*C7,  -.5*C3 },
 {  .5*C4,  -.5*C4,  -.5*C4,   .5*C4,   .5*C4,  -.5*C4,  -.5*C4,   .5*C4 },
 {  .5*C5,  -.5*C1,   .5*C7,   .5*C3,  -.5*C3,  -.5*C7,   .5*C1,  -.5*C5 },
 {  .5*C6,  -.5*C2,   .5*C2,  -.5*C6,  -.5*C6,   .5*C2,  -.5*C2,   .5*C6 },
 {  .5*C7,  -.5*C5,   .5*C3,  -.5*C1,   .5*C1,  -.5*C3,   .5*C5,  -.5*C7 },
};
// f32 copy for the post-quantization (smooth) path.
#define ROWF(r) {(float)Mc[r][0],(float)Mc[r][1],(float)Mc[r][2],(float)Mc[r][3],\
                 (float)Mc[r][4],(float)Mc[r][5],(float)Mc[r][6],(float)Mc[r][7]}
static constexpr float Mcf[8][8] = {ROWF(0),ROWF(1),ROWF(2),ROWF(3),ROWF(4),ROWF(5),ROWF(6),ROWF(7)};

// JPEG base quantization tables (exact integers)
static __device__ const double LUM_BASE[64] = {
 16,11,10,16,24,40,51,61,
 12,12,14,19,26,58,60,55,
 14,13,16,24,40,57,69,56,
 14,17,22,29,51,87,80,62,
 18,22,37,56,68,109,103,77,
 24,35,55,64,81,104,113,92,
 49,64,78,87,103,121,120,101,
 72,92,95,98,112,100,103,99};
static __device__ const double CHROM_BASE[64] = {
 17,18,24,47,99,99,99,99,
 18,21,26,66,99,99,99,99,
 24,26,56,99,99,99,99,99,
 47,66,99,99,99,99,99,99,
 99,99,99,99,99,99,99,99,
 99,99,99,99,99,99,99,99,
 99,99,99,99,99,99,99,99,
 99,99,99,99,99,99,99,99};

// Wave-level LDS fence: pins compiler ordering (memory clobber) AND drains
// LDS writes (lgkmcnt). Replaces __syncthreads() for 1-wave blocks.
#define WAVE_FENCE() asm volatile("s_waitcnt lgkmcnt(0)" ::: "memory")

// Round 13: ONE WAVE PER STRIP, all 3 channels per thread, ZERO barriers
// (106.2 us, bit-identical). Round 14 (this): occupancy lever —
// - QT/RQ merged into interleaved QR[{q,1/q}] and read IN-LOOP in P2 as one
//   16B LDS broadcast read per j (conflict-free), shrinking the q/r live
//   range from whole-kernel (32 VGPRs) to inside-P2.
// - __launch_bounds__(64,4): VGPR cap 128 -> 4 waves/EU, 16 blocks/CU
//   (LDS 8.96KB x 16 = 143KB <= 160KB, not limiting).
// Same values, same expression trees -> bit-identical output.
__global__ __launch_bounds__(64, 4) void jpeg_fwd(const float* __restrict__ img,
                                                  const int* __restrict__ quality,
                                                  float* __restrict__ out)
{
    __shared__ double QR[256];     // [2][8][8][2] = interleaved {q, 1/q}, 2048 B
    __shared__ double U64[576];    // f64 transpose-1 buffer (pad-9), 4608 B
    __shared__ float  U32[576];    // f32 transpose-2 buffer (pad-9), 2304 B

    const int l   = threadIdx.x;   // 0..63
    const int blk = l >> 3;        // block within strip (0..7)
    const int rr  = l & 7;         // row within block

    const int b    = blockIdx.x >> 9;   // image index
    const int rem  = blockIdx.x & 511;
    const int row0 = (rem >> 3) << 3;   // strip row * 8
    const int col0 = (rem & 7) << 6;    // strip col * 64

    const size_t plane = 512 * 512;

    // ---- Issue global loads early (my row's 8 px, all 3 planes, float4)
    const float* p = img + (size_t)(b * 3) * plane + (size_t)(row0 + rr) * 512 + col0 + blk * 8;
    float4 R0 = *(const float4*)(p);
    float4 R1 = *(const float4*)(p + 4);
    float4 G0 = *(const float4*)(p + plane);
    float4 G1 = *(const float4*)(p + plane + 4);
    float4 B0 = *(const float4*)(p + 2 * plane);
    float4 B1 = *(const float4*)(p + 2 * plane + 4);

    // ---- Build quant table + reciprocals in LDS — all 64 lanes, 2 entries
    // each (R0 pattern). Cross-lane RAW protected by the wave fence below.
    // Arithmetic identical to previous rounds -> bit-identical {q, 1/q}.
    {
        int q = quality[0];
        q = q < 1 ? 1 : (q > 100 ? 100 : q);
        double scale = (q < 50) ? (5000.0 / (double)q) : (200.0 - 2.0 * (double)q);
        #pragma unroll
        for (int h = 0; h < 2; ++h) {
            int e = l + (h << 6);           // entries l and l+64 -> covers 0..127
            int tbl = e >> 6, idx = e & 63;
            double base = tbl ? CHROM_BASE[idx] : LUM_BASE[idx];
            double v = (base * scale + 50.0) / 100.0;
            v = fmin(fmax(v, 1.0), 255.0);
            QR[2 * e]     = v;
            QR[2 * e + 1] = 1.0 / v;
        }
    }
    WAVE_FENCE();   // QR visible to all lanes of this (only) wave

    // YCbCr weights with x255 folded in at compile time (f64 products).
    const double F00 =  0.299 * 255.0,  F01 =  0.587 * 255.0,  F02 =  0.114 * 255.0;
    const double F10 = -0.1687 * 255.0, F11 = -0.3313 * 255.0, F12 =  0.5 * 255.0;
    const double F20 =  0.5 * 255.0,    F21 = -0.4187 * 255.0, F22 = -0.0813 * 255.0;

    float rf[8] = {R0.x, R0.y, R0.z, R0.w, R1.x, R1.y, R1.z, R1.w};
    float gf[8] = {G0.x, G0.y, G0.z, G0.w, G1.x, G1.y, G1.z, G1.w};
    float bf[8] = {B0.x, B0.y, B0.z, B0.w, B1.x, B1.y, B1.z, B1.w};

    float pix0[8], pix1[8], pix2[8];   // final IDCT pixel rows Y, Cb, Cr

    // ================= per-channel pipeline (macro: CIDX is a literal) =====
#define CHANNEL_BODY(CIDX, PIXARR, COLOR_EXPR)                                  \
    {                                                                           \
        /* quant-table base for this channel (reference's flattened quirk) */   \
        const int sel_c = ((b * 3 + CIDX) < 16) ? 0 : 1;                        \
        const double* QRb = QR + (((sel_c << 6) + rr) << 1);                    \
        /* ---- Color convert (f64), keep +128 then -128 (both roundings) */   \
        double row[8];                                                          \
        _Pragma("unroll")                                                       \
        for (int k = 0; k < 8; ++k) {                                           \
            double rv = (double)rf[k];                                          \
            double gv = (double)gf[k];                                          \
            double bv = (double)bf[k];                                          \
            double v  = (COLOR_EXPR);                                           \
            row[k] = v - 128.0;                                                 \
        }                                                                       \
        /* ---- P1: row @ M^T via even-odd symmetry (f64) */                    \
        double y[8];                                                            \
        {                                                                       \
            double u0[4], v0[4];                                                \
            _Pragma("unroll")                                                   \
            for (int k = 0; k < 4; ++k) {                                       \
                u0[k] = row[k] + row[7 - k];                                    \
                v0[k] = row[k] - row[7 - k];                                    \
            }                                                                   \
            _Pragma("unroll")                                                   \
            for (int c = 0; c < 8; c += 2) {                                    \
                double se = 0.0, so = 0.0;                                      \
                _Pragma("unroll")                                               \
                for (int k = 0; k < 4; ++k) {                                   \
                    se += u0[k] * Mc[c][k];                                     \
                    so += v0[k] * Mc[c + 1][k];                                 \
                }                                                               \
                y[c] = se; y[c + 1] = so;                                       \
            }                                                                   \
        }                                                                       \
        /* ---- Transpose 1 (f64, pad-9, in-wave, fenced) */                    \
        {                                                                       \
            double* tb = U64 + blk * 72 + rr * 9;                               \
            _Pragma("unroll")                                                   \
            for (int k = 0; k < 8; ++k) tb[k] = y[k];                           \
        }                                                                       \
        WAVE_FENCE();                                                           \
        double t1[8];                                                           \
        {                                                                       \
            const double* tb = U64 + blk * 72 + rr;                             \
            _Pragma("unroll")                                                   \
            for (int k = 0; k < 8; ++k) t1[k] = tb[k * 9];                      \
        }                                                                       \
        /* ---- P2: column DCT (even-odd) + quantize tq = rint(s/q)*q.       */ \
        /* {q, 1/q} fetched per-j as one 16B LDS broadcast read (8 distinct  */ \
        /* addresses, 8-lane broadcast groups -> conflict-free).             */ \
        double wq[8];                                                           \
        {                                                                       \
            double tu[4], tv[4];                                                \
            _Pragma("unroll")                                                   \
            for (int k = 0; k < 4; ++k) {                                       \
                tu[k] = t1[k] + t1[7 - k];                                      \
                tv[k] = t1[k] - t1[7 - k];                                      \
            }                                                                   \
            _Pragma("unroll")                                                   \
            for (int j = 0; j < 8; j += 2) {                                    \
                double se = 0.0, so = 0.0;                                      \
                _Pragma("unroll")                                               \
                for (int k = 0; k < 4; ++k) {                                   \
                    se += tu[k] * Mc[j][k];                                     \
                    so += tv[k] * Mc[j + 1][k];                                 \
                }                                                               \
                { /* even j: Markstein reciprocal division, bit-identical */    \
                    double q = QRb[(j << 4)];                                   \
                    double r = QRb[(j << 4) + 1];                               \
                    double qh = se * r;                                         \
                    double e  = fma(-q, qh, se);                                \
                    double qq = fma(e, r, qh);                                  \
                    wq[j] = rint(qq) * q;                                       \
                }                                                               \
                { /* odd j */                                                   \
                    double q = QRb[((j + 1) << 4)];                             \
                    double r = QRb[((j + 1) << 4) + 1];                         \
                    double qh = so * r;                                         \
                    double e  = fma(-q, qh, so);                                \
                    double qq = fma(e, r, qh);                                  \
                    wq[j + 1] = rint(qq) * q;                                   \
                }                                                               \
            }                                                                   \
        }                                                                       \
        /* ======== post-cliff: f32 ======== */                                 \
        float wqf[8];                                                           \
        _Pragma("unroll")                                                       \
        for (int k = 0; k < 8; ++k) wqf[k] = (float)wq[k];                      \
        /* ---- P3: (tq^T row) @ M (f32, even-odd over output index j) */       \
        float a3[8];                                                            \
        _Pragma("unroll")                                                       \
        for (int j = 0; j < 4; ++j) {                                           \
            float pe = 0.0f, po = 0.0f;                                         \
            _Pragma("unroll")                                                   \
            for (int k = 0; k < 4; ++k) {                                       \
                pe += wqf[2 * k]     * Mcf[2 * k][j];                           \
                po += wqf[2 * k + 1] * Mcf[2 * k + 1][j];                       \
            }                                                                   \
            a3[j]     = pe + po;                                                \
            a3[7 - j] = pe - po;                                                \
        }                                                                       \
        /* ---- Transpose 2 (f32, pad-9, in-wave, fenced; own buffer) */        \
        {                                                                       \
            float* tb = U32 + blk * 72 + rr * 9;                                \
            _Pragma("unroll")                                                   \
            for (int k = 0; k < 8; ++k) tb[k] = a3[k];                          \
        }                                                                       \
        WAVE_FENCE();                                                           \
        float tC[8];                                                            \
        {                                                                       \
            const float* c2 = U32 + blk * 72 + rr;                              \
            _Pragma("unroll")                                                   \
            for (int k = 0; k < 8; ++k) tC[k] = c2[k * 9];                      \
        }                                                                       \
        /* ---- P4 (f32, even-odd): final IDCT row rr for this channel */       \
        _Pragma("unroll")                                                       \
        for (int j = 0; j < 4; ++j) {                                           \
            float e = 0.0f, o = 0.0f;                                           \
            _Pragma("unroll")                                                   \
            for (int k = 0; k < 4; ++k) {                                       \
                e += tC[2 * k]     * Mcf[2 * k][j];                             \
                o += tC[2 * k + 1] * Mcf[2 * k + 1][j];                         \
            }                                                                   \
            PIXARR[j]     = e + o;                                              \
            PIXARR[7 - j] = e - o;                                              \
        }                                                                       \
        WAVE_FENCE(); /* WAR: next channel's LDS writes must stay behind */     \
    }

    CHANNEL_BODY(0, pix0, F00 * rv + F01 * gv + F02 * bv)
    CHANNEL_BODY(1, pix1, F10 * rv + F11 * gv + F12 * bv + 128.0)
    CHANNEL_BODY(2, pix2, F20 * rv + F21 * gv + F22 * bv + 128.0)
#undef CHANNEL_BODY

    // ---- Color back (f32), all in registers; exact same expression trees.
    float oR[8], oG[8], oB[8];
    #pragma unroll
    for (int k = 0; k < 8; ++k) {
        float yd = pix0[k] + 128.0f;
        float vR = yd + 1.402f * pix2[k];
        float vG = yd - 0.34414f * pix1[k] - 0.71414f * pix2[k];
        float vB = yd + 1.772f * pix1[k];
        oR[k] = fminf(fmaxf(vR * (1.0f / 255.0f), 0.0f), 1.0f);
        oG[k] = fminf(fmaxf(vG * (1.0f / 255.0f), 0.0f), 1.0f);
        oB[k] = fminf(fmaxf(vB * (1.0f / 255.0f), 0.0f), 1.0f);
    }

    // ---- Stores: 3 planes x 2 float4, coalesced per instruction
    const size_t rowoff = (size_t)(row0 + rr) * 512 + col0 + blk * 8;
    float* qR = out + (size_t)(b * 3 + 0) * plane + rowoff;
    float* qG = out + (size_t)(b * 3 + 1) * plane + rowoff;
    float* qB = out + (size_t)(b * 3 + 2) * plane + rowoff;
    *(float4*)(qR)     = make_float4(oR[0], oR[1], oR[2], oR[3]);
    *(float4*)(qR + 4) = make_float4(oR[4], oR[5], oR[6], oR[7]);
    *(float4*)(qG)     = make_float4(oG[0], oG[1], oG[2], oG[3]);
    *(float4*)(qG + 4) = make_float4(oG[4], oG[5], oG[6], oG[7]);
    *(float4*)(qB)     = make_float4(oB[0], oB[1], oB[2], oB[3]);
    *(float4*)(qB + 4) = make_float4(oB[4], oB[5], oB[6], oB[7]);
}

extern "C" void kernel_launch(void* const* d_in, const int* in_sizes, int n_in,
                              void* d_out, int out_size, void* d_ws, size_t ws_size,
                              hipStream_t stream) {
    const float* img     = (const float*)d_in[0];
    const int*   quality = (const int*)d_in[1];
    float*       out     = (float*)d_out;
    // 16 images x 64 row-strips x 8 col-strips = 8192 strips, 1 wave each
    jpeg_fwd<<<8192, 64, 0, stream>>>(img, quality, out);
}